// Round 1
// baseline (1397.497 us; speedup 1.0000x reference)
//
#include <hip/hip_runtime.h>

// MaxPool 2x2, stride 2, fp32.
// Input : (16, 64, 512, 512)  = 268,435,456 floats
// Output: (16, 64, 256, 256)  =  67,108,864 floats
//
// One lane -> one float4 of output (4 output cols) from 8 input cols x 2 rows.
// A 64-lane wave covers one full output row (256 floats) and reads two full
// contiguous input rows -> fully coalesced 16B/lane loads and stores.

#define IN_W   512
#define OUT_W  256
#define OUT_H  256

__global__ __launch_bounds__(256) void maxpool2x2_kernel(
    const float* __restrict__ in, float* __restrict__ out, int n_vec4)
{
    int t = blockIdx.x * blockDim.x + threadIdx.x;
    if (t >= n_vec4) return;

    // t indexes float4's of output. 64 float4 per output row.
    int ow4 = t & 63;          // which float4 within the output row
    int row = t >> 6;          // global output row: bc*256 + oh
    int oh  = row & (OUT_H - 1);
    int bc  = row >> 8;        // fused batch*channel index

    const float* base = in + (size_t)bc * (IN_W * IN_W)
                           + (size_t)(oh * 2) * IN_W
                           + ow4 * 8;

    const float4* p0 = (const float4*)base;            // row 2*oh
    const float4* p1 = (const float4*)(base + IN_W);   // row 2*oh + 1

    float4 a0 = p0[0];
    float4 a1 = p0[1];
    float4 b0 = p1[0];
    float4 b1 = p1[1];

    float4 r;
    r.x = fmaxf(fmaxf(a0.x, a0.y), fmaxf(b0.x, b0.y));
    r.y = fmaxf(fmaxf(a0.z, a0.w), fmaxf(b0.z, b0.w));
    r.z = fmaxf(fmaxf(a1.x, a1.y), fmaxf(b1.x, b1.y));
    r.w = fmaxf(fmaxf(a1.z, a1.w), fmaxf(b1.z, b1.w));

    ((float4*)out)[t] = r;
}

extern "C" void kernel_launch(void* const* d_in, const int* in_sizes, int n_in,
                              void* d_out, int out_size, void* d_ws, size_t ws_size,
                              hipStream_t stream) {
    const float* in = (const float*)d_in[0];
    float* out = (float*)d_out;

    int n_vec4 = out_size / 4;               // 16,777,216
    int block = 256;
    int grid = (n_vec4 + block - 1) / block; // 65,536

    maxpool2x2_kernel<<<grid, block, 0, stream>>>(in, out, n_vec4);
}